// Round 1
// baseline (1351.646 us; speedup 1.0000x reference)
//
#include <hip/hip_runtime.h>
#include <hip/hip_bf16.h>

// Problem constants (RelKDAdapter_60284160966709)
#define D_SRC 256
#define D_REL 128

// ---------------- GEMM: src_proj = x_src @ W_src  (fp32 vector) ----------------
// M x 256 @ 256 x 128. Tile BM=64, BN=128, BK=32. Block = 256 threads.
// Thread tile TM=4 x TN=8 (16x16 thread grid).
#define BM 64
#define BN 128
#define BK 32
#define TM 4
#define TN 8

__global__ __launch_bounds__(256) void gemm_src_proj(
    const float* __restrict__ A,   // [M, 256]
    const float* __restrict__ B,   // [256, 128]
    float* __restrict__ C,         // [M, 128]
    int M) {
  __shared__ float As[BM][BK + 4];   // +4 pad keeps 16B alignment, breaks pow2 stride
  __shared__ float Bs[BK][BN + 4];

  const int t = threadIdx.x;
  const int block_row = blockIdx.x * BM;
  const int tx = t & 15;   // 16 col groups of TN=8
  const int ty = t >> 4;   // 16 row groups of TM=4

  float acc[TM][TN];
#pragma unroll
  for (int i = 0; i < TM; ++i)
#pragma unroll
    for (int j = 0; j < TN; ++j) acc[i][j] = 0.f;

  for (int k0 = 0; k0 < D_SRC; k0 += BK) {
    // Load A tile: 64 rows x 32 cols = 2048 floats; 8 floats (2x float4) per thread
    {
      const int r = t >> 3;            // 0..31
      const int c4 = (t & 7) << 2;     // 0,4,...,28
#pragma unroll
      for (int rr = 0; rr < 2; ++rr) {
        const int row = r + rr * 32;
        const int grow = block_row + row;
        float4 v = make_float4(0.f, 0.f, 0.f, 0.f);
        if (grow < M) v = *(const float4*)(A + (size_t)grow * D_SRC + k0 + c4);
        *(float4*)(&As[row][c4]) = v;
      }
    }
    // Load B tile: 32 rows x 128 cols = 4096 floats; 16 floats (4x float4) per thread
    {
      const int kr = t >> 5;           // 0..7
      const int c4 = (t & 31) << 2;    // 0..124
#pragma unroll
      for (int kk = 0; kk < 4; ++kk) {
        const int krow = kr + kk * 8;
        float4 v = *(const float4*)(B + (size_t)(k0 + krow) * D_REL + c4);
        *(float4*)(&Bs[krow][c4]) = v;
      }
    }
    __syncthreads();

#pragma unroll
    for (int k = 0; k < BK; ++k) {
      float a[TM], b[TN];
#pragma unroll
      for (int i = 0; i < TM; ++i) a[i] = As[ty * TM + i][k];
      float4 b0 = *(const float4*)(&Bs[k][tx * TN]);
      float4 b1 = *(const float4*)(&Bs[k][tx * TN + 4]);
      b[0] = b0.x; b[1] = b0.y; b[2] = b0.z; b[3] = b0.w;
      b[4] = b1.x; b[5] = b1.y; b[6] = b1.z; b[7] = b1.w;
#pragma unroll
      for (int i = 0; i < TM; ++i)
#pragma unroll
        for (int j = 0; j < TN; ++j) acc[i][j] = fmaf(a[i], b[j], acc[i][j]);
    }
    __syncthreads();
  }

  // Store C: each thread writes TM rows x TN cols (2 float4 per row)
#pragma unroll
  for (int i = 0; i < TM; ++i) {
    const int grow = block_row + ty * TM + i;
    if (grow < M) {
      float4 o0 = make_float4(acc[i][0], acc[i][1], acc[i][2], acc[i][3]);
      float4 o1 = make_float4(acc[i][4], acc[i][5], acc[i][6], acc[i][7]);
      float* dst = C + (size_t)grow * D_REL + tx * TN;
      *(float4*)(dst) = o0;
      *(float4*)(dst + 4) = o1;
    }
  }
}

// ---------------- Degree count ----------------
__global__ __launch_bounds__(256) void deg_count(
    const int* __restrict__ edge_row, int E, int* __restrict__ cnt) {
  int i = blockIdx.x * blockDim.x + threadIdx.x;
  if (i < E) atomicAdd(&cnt[edge_row[i]], 1);
}

// deg_out = max(cnt,1) as float; inv_deg = 1/deg
__global__ __launch_bounds__(256) void deg_finalize(
    const int* __restrict__ cnt, int n,
    float* __restrict__ deg_out, float* __restrict__ inv_deg) {
  int i = blockIdx.x * blockDim.x + threadIdx.x;
  if (i < n) {
    int c = cnt[i];
    float d = (float)(c > 1 ? c : 1);
    deg_out[i] = d;
    inv_deg[i] = 1.0f / d;
  }
}

// ---------------- Aggregation: dst[row] += src_proj[col] * inv_deg[row] ----------------
// 32 threads per edge; each thread handles one float4 (4 features).
__global__ __launch_bounds__(256) void aggregate(
    const int* __restrict__ edge_row, const int* __restrict__ edge_col,
    const float* __restrict__ src_proj, const float* __restrict__ inv_deg,
    float* __restrict__ dst, int E) {
  long long idx = (long long)blockIdx.x * blockDim.x + threadIdx.x;
  long long total = (long long)E * 32;
  if (idx >= total) return;
  int e = (int)(idx >> 5);
  int chunk = (int)(idx & 31);
  int row = edge_row[e];
  int col = edge_col[e];
  float w = inv_deg[row];
  float4 v = *(const float4*)(src_proj + (size_t)col * D_REL + chunk * 4);
  float* d = dst + (size_t)row * D_REL + chunk * 4;
  atomicAdd(d + 0, v.x * w);
  atomicAdd(d + 1, v.y * w);
  atomicAdd(d + 2, v.z * w);
  atomicAdd(d + 3, v.w * w);
}

extern "C" void kernel_launch(void* const* d_in, const int* in_sizes, int n_in,
                              void* d_out, int out_size, void* d_ws, size_t ws_size,
                              hipStream_t stream) {
  const float* x_src = (const float*)d_in[0];
  // d_in[1] = x_dst, d_in[3] = W_dst: dead (dst_proj is deleted in reference)
  const float* W_src = (const float*)d_in[2];
  const int* edge_row = (const int*)d_in[4];
  const int* edge_col = (const int*)d_in[5];

  const int M = in_sizes[0] / D_SRC;       // N_SRC = 100000
  const int N_DST_n = in_sizes[1] / 64;    // N_DST = 100000
  const int E = in_sizes[4];               // 640000

  float* out = (float*)d_out;
  float* out_dst = out;                                        // [N_DST, 128]
  float* out_src_proj = out + (size_t)N_DST_n * D_REL;         // [N_SRC, 128]
  float* out_deg = out + (size_t)N_DST_n * D_REL + (size_t)M * D_REL;  // [N_DST]

  // workspace: cnt int[N_DST] at 0; inv_deg float[N_DST] after
  int* cnt = (int*)d_ws;
  float* inv_deg = (float*)((char*)d_ws + ((size_t)N_DST_n * sizeof(int) + 511) / 512 * 512);

  // Zero-init dst region and counts (d_out/d_ws are poisoned 0xAA each call)
  hipMemsetAsync(out_dst, 0, (size_t)N_DST_n * D_REL * sizeof(float), stream);
  hipMemsetAsync(cnt, 0, (size_t)N_DST_n * sizeof(int), stream);

  // Degree
  deg_count<<<(E + 255) / 256, 256, 0, stream>>>(edge_row, E, cnt);
  deg_finalize<<<(N_DST_n + 255) / 256, 256, 0, stream>>>(cnt, N_DST_n, out_deg, inv_deg);

  // GEMM src_proj
  gemm_src_proj<<<(M + BM - 1) / BM, 256, 0, stream>>>(x_src, W_src, out_src_proj, M);

  // Aggregate
  long long total = (long long)E * 32;
  int blocks = (int)((total + 255) / 256);
  aggregate<<<blocks, 256, 0, stream>>>(edge_row, edge_col, out_src_proj, inv_deg,
                                        out_dst, E);
}

// Round 2
// 386.808 us; speedup vs baseline: 3.4944x; 3.4944x over previous
//
#include <hip/hip_runtime.h>
#include <hip/hip_bf16.h>

// Problem constants (RelKDAdapter_60284160966709)
#define D_SRC 256
#define D_REL 128

// ---------------- GEMM: src_proj = x_src @ W_src  (fp32 vector) ----------------
#define BM 64
#define BN 128
#define BK 32
#define TM 4
#define TN 8

__global__ __launch_bounds__(256) void gemm_src_proj(
    const float* __restrict__ A,   // [M, 256]
    const float* __restrict__ B,   // [256, 128]
    float* __restrict__ C,         // [M, 128]
    int M) {
  __shared__ float As[BM][BK + 4];
  __shared__ float Bs[BK][BN + 4];

  const int t = threadIdx.x;
  const int block_row = blockIdx.x * BM;
  const int tx = t & 15;
  const int ty = t >> 4;

  float acc[TM][TN];
#pragma unroll
  for (int i = 0; i < TM; ++i)
#pragma unroll
    for (int j = 0; j < TN; ++j) acc[i][j] = 0.f;

  for (int k0 = 0; k0 < D_SRC; k0 += BK) {
    {
      const int r = t >> 3;
      const int c4 = (t & 7) << 2;
#pragma unroll
      for (int rr = 0; rr < 2; ++rr) {
        const int row = r + rr * 32;
        const int grow = block_row + row;
        float4 v = make_float4(0.f, 0.f, 0.f, 0.f);
        if (grow < M) v = *(const float4*)(A + (size_t)grow * D_SRC + k0 + c4);
        *(float4*)(&As[row][c4]) = v;
      }
    }
    {
      const int kr = t >> 5;
      const int c4 = (t & 31) << 2;
#pragma unroll
      for (int kk = 0; kk < 4; ++kk) {
        const int krow = kr + kk * 8;
        float4 v = *(const float4*)(B + (size_t)(k0 + krow) * D_REL + c4);
        *(float4*)(&Bs[krow][c4]) = v;
      }
    }
    __syncthreads();

#pragma unroll
    for (int k = 0; k < BK; ++k) {
      float a[TM], b[TN];
#pragma unroll
      for (int i = 0; i < TM; ++i) a[i] = As[ty * TM + i][k];
      float4 b0 = *(const float4*)(&Bs[k][tx * TN]);
      float4 b1 = *(const float4*)(&Bs[k][tx * TN + 4]);
      b[0] = b0.x; b[1] = b0.y; b[2] = b0.z; b[3] = b0.w;
      b[4] = b1.x; b[5] = b1.y; b[6] = b1.z; b[7] = b1.w;
#pragma unroll
      for (int i = 0; i < TM; ++i)
#pragma unroll
        for (int j = 0; j < TN; ++j) acc[i][j] = fmaf(a[i], b[j], acc[i][j]);
    }
    __syncthreads();
  }

#pragma unroll
  for (int i = 0; i < TM; ++i) {
    const int grow = block_row + ty * TM + i;
    if (grow < M) {
      float4 o0 = make_float4(acc[i][0], acc[i][1], acc[i][2], acc[i][3]);
      float4 o1 = make_float4(acc[i][4], acc[i][5], acc[i][6], acc[i][7]);
      float* dst = C + (size_t)grow * D_REL + tx * TN;
      *(float4*)(dst) = o0;
      *(float4*)(dst + 4) = o1;
    }
  }
}

// ---------------- Degree count ----------------
__global__ __launch_bounds__(256) void deg_count(
    const int* __restrict__ edge_row, int E, int* __restrict__ cnt) {
  int i = blockIdx.x * blockDim.x + threadIdx.x;
  if (i < E) atomicAdd(&cnt[edge_row[i]], 1);
}

// deg_out = max(cnt,1) as float; inv_deg = 1/deg
__global__ __launch_bounds__(256) void deg_finalize(
    const int* __restrict__ cnt, int n,
    float* __restrict__ deg_out, float* __restrict__ inv_deg) {
  int i = blockIdx.x * blockDim.x + threadIdx.x;
  if (i < n) {
    int c = cnt[i];
    float d = (float)(c > 1 ? c : 1);
    deg_out[i] = d;
    inv_deg[i] = 1.0f / d;
  }
}

// ---------------- Exclusive scan of cnt -> row_ptr (3 kernels) ----------------
#define SCAN_B 256

// Per-block Hillis-Steele inclusive scan; writes exclusive partials + block totals.
__global__ __launch_bounds__(SCAN_B) void scan1(
    const int* __restrict__ cnt, int n,
    int* __restrict__ row_ptr, int* __restrict__ block_sums) {
  __shared__ int s[SCAN_B];
  int i = blockIdx.x * SCAN_B + threadIdx.x;
  int v = (i < n) ? cnt[i] : 0;
  s[threadIdx.x] = v;
  __syncthreads();
#pragma unroll
  for (int off = 1; off < SCAN_B; off <<= 1) {
    int add = (threadIdx.x >= off) ? s[threadIdx.x - off] : 0;
    __syncthreads();
    s[threadIdx.x] += add;
    __syncthreads();
  }
  if (i < n) row_ptr[i] = s[threadIdx.x] - v;  // exclusive
  if (threadIdx.x == SCAN_B - 1) block_sums[blockIdx.x] = s[SCAN_B - 1];
}

// Single-block scan of block sums (nblocks <= 512).
__global__ __launch_bounds__(512) void scan2(
    int* __restrict__ block_sums, int nblocks) {
  __shared__ int s[512];
  int v = (threadIdx.x < nblocks) ? block_sums[threadIdx.x] : 0;
  s[threadIdx.x] = v;
  __syncthreads();
#pragma unroll
  for (int off = 1; off < 512; off <<= 1) {
    int add = (threadIdx.x >= off) ? s[threadIdx.x - off] : 0;
    __syncthreads();
    s[threadIdx.x] += add;
    __syncthreads();
  }
  if (threadIdx.x < nblocks) block_sums[threadIdx.x] = s[threadIdx.x] - v;  // exclusive
}

// Add block offsets; also fill cursor copy and row_ptr[n] = E.
__global__ __launch_bounds__(SCAN_B) void scan3(
    int* __restrict__ row_ptr, const int* __restrict__ block_sums,
    int* __restrict__ cursor, int n, int E) {
  int i = blockIdx.x * SCAN_B + threadIdx.x;
  if (i < n) {
    int v = row_ptr[i] + block_sums[blockIdx.x];
    row_ptr[i] = v;
    cursor[i] = v;
  }
  if (i == 0) row_ptr[n] = E;
}

// ---------------- Scatter edges into CSR order ----------------
__global__ __launch_bounds__(256) void scatter_edges(
    const int* __restrict__ edge_row, const int* __restrict__ edge_col,
    int* __restrict__ cursor, int* __restrict__ sorted_col, int E) {
  int e = blockIdx.x * blockDim.x + threadIdx.x;
  if (e < E) {
    int r = edge_row[e];
    int pos = atomicAdd(&cursor[r], 1);
    sorted_col[pos] = edge_col[e];
  }
}

// ---------------- CSR aggregate: one wave per dst row ----------------
// Each lane owns 2 features (float2). For each edge: coalesced 512B row read.
__global__ __launch_bounds__(256) void aggregate_csr(
    const int* __restrict__ row_ptr, const int* __restrict__ sorted_col,
    const float* __restrict__ src_proj, const float* __restrict__ inv_deg,
    float* __restrict__ dst, int n) {
  int wave = (blockIdx.x * blockDim.x + threadIdx.x) >> 6;
  int lane = threadIdx.x & 63;
  if (wave >= n) return;
  int beg = row_ptr[wave];
  int end = row_ptr[wave + 1];
  const float* base = src_proj + lane * 2;
  float ax = 0.f, ay = 0.f, bx = 0.f, by = 0.f;
  int e = beg;
  for (; e + 1 < end; e += 2) {
    int c0 = sorted_col[e];
    int c1 = sorted_col[e + 1];
    float2 v0 = *(const float2*)(base + (size_t)c0 * D_REL);
    float2 v1 = *(const float2*)(base + (size_t)c1 * D_REL);
    ax += v0.x; ay += v0.y;
    bx += v1.x; by += v1.y;
  }
  if (e < end) {
    int c0 = sorted_col[e];
    float2 v0 = *(const float2*)(base + (size_t)c0 * D_REL);
    ax += v0.x; ay += v0.y;
  }
  float w = inv_deg[wave];
  float2 o;
  o.x = (ax + bx) * w;
  o.y = (ay + by) * w;
  *(float2*)(dst + (size_t)wave * D_REL + lane * 2) = o;
}

extern "C" void kernel_launch(void* const* d_in, const int* in_sizes, int n_in,
                              void* d_out, int out_size, void* d_ws, size_t ws_size,
                              hipStream_t stream) {
  const float* x_src = (const float*)d_in[0];
  // d_in[1] = x_dst, d_in[3] = W_dst: dead (dst_proj is deleted in reference)
  const float* W_src = (const float*)d_in[2];
  const int* edge_row = (const int*)d_in[4];
  const int* edge_col = (const int*)d_in[5];

  const int M = in_sizes[0] / D_SRC;       // N_SRC = 100000
  const int N = in_sizes[1] / 64;          // N_DST = 100000
  const int E = in_sizes[4];               // 640000

  float* out = (float*)d_out;
  float* out_dst = out;                                      // [N, 128]
  float* out_src_proj = out + (size_t)N * D_REL;             // [M, 128]
  float* out_deg = out_src_proj + (size_t)M * D_REL;         // [N]

  // Workspace layout (all 256B-aligned)
  char* ws = (char*)d_ws;
  size_t off = 0;
  auto alloc = [&](size_t bytes) {
    char* p = ws + off;
    off = (off + bytes + 255) & ~(size_t)255;
    return p;
  };
  int* cnt        = (int*)alloc((size_t)N * sizeof(int));
  int* row_ptr    = (int*)alloc((size_t)(N + 1) * sizeof(int));
  int* cursor     = (int*)alloc((size_t)N * sizeof(int));
  int* sorted_col = (int*)alloc((size_t)E * sizeof(int));
  float* inv_deg  = (float*)alloc((size_t)N * sizeof(float));
  int* block_sums = (int*)alloc(512 * sizeof(int));
  (void)ws_size;

  const int scan_blocks = (N + SCAN_B - 1) / SCAN_B;  // 391 <= 512

  hipMemsetAsync(cnt, 0, (size_t)N * sizeof(int), stream);

  // Degree + inv_deg
  deg_count<<<(E + 255) / 256, 256, 0, stream>>>(edge_row, E, cnt);
  deg_finalize<<<(N + 255) / 256, 256, 0, stream>>>(cnt, N, out_deg, inv_deg);

  // Exclusive scan cnt -> row_ptr; cursor = row_ptr
  scan1<<<scan_blocks, SCAN_B, 0, stream>>>(cnt, N, row_ptr, block_sums);
  scan2<<<1, 512, 0, stream>>>(block_sums, scan_blocks);
  scan3<<<scan_blocks, SCAN_B, 0, stream>>>(row_ptr, block_sums, cursor, N, E);

  // CSR scatter
  scatter_edges<<<(E + 255) / 256, 256, 0, stream>>>(edge_row, edge_col, cursor,
                                                     sorted_col, E);

  // GEMM src_proj
  gemm_src_proj<<<(M + BM - 1) / BM, 256, 0, stream>>>(x_src, W_src, out_src_proj, M);

  // Gather-aggregate: 1 wave per dst row, 4 waves per block
  aggregate_csr<<<(N + 3) / 4, 256, 0, stream>>>(row_ptr, sorted_col, out_src_proj,
                                                 inv_deg, out_dst, N);
}

// Round 3
// 349.108 us; speedup vs baseline: 3.8717x; 1.1080x over previous
//
#include <hip/hip_runtime.h>
#include <hip/hip_bf16.h>

// Problem constants (RelKDAdapter_60284160966709)
#define D_SRC 256
#define D_REL 128

typedef short bf16x8 __attribute__((ext_vector_type(8)));
typedef float f32x4 __attribute__((ext_vector_type(4)));

__device__ __forceinline__ unsigned short f2bf(float f) {
  unsigned u = __float_as_uint(f);
  unsigned r = 0x7FFFu + ((u >> 16) & 1u);
  return (unsigned short)((u + r) >> 16);
}

// ---------------- W^T bf16 conversion: WT[n][k] = bf16(W[k][n]) ----------------
__global__ __launch_bounds__(256) void convert_wt(
    const float* __restrict__ W, unsigned short* __restrict__ WT) {
  int idx = blockIdx.x * 256 + threadIdx.x;  // 32768 total
  int n = idx >> 8;    // 0..127
  int k = idx & 255;   // 0..255
  WT[idx] = f2bf(W[(size_t)k * D_REL + n]);  // coalesced write, strided read (L2)
}

// ---------------- MFMA bf16 GEMM: C = A @ W  (A fp32 converted on the fly) ----------------
// BM=128 rows/block, BN=128 (=full N), BK=32. 256 threads = 4 waves in 2x2 grid,
// each wave computes 64x64 via 4x4 tiles of mfma_f32_16x16x32_bf16.
#define GBM 128
#define GBK 32
#define APAD 8   // +8 shorts (16B) pad: keeps 16B alignment, 2-way (free) bank aliasing

__global__ __launch_bounds__(256) void gemm_mfma(
    const float* __restrict__ A,            // [M, 256] fp32
    const unsigned short* __restrict__ WT,  // [128, 256] bf16 bits (n-major)
    float* __restrict__ C,                  // [M, 128] fp32 out
    unsigned short* __restrict__ Cbf,       // [M, 128] bf16 copy (may be unused)
    int M, int write_bf) {
  __shared__ unsigned short As[GBM][GBK + APAD];
  __shared__ unsigned short Bs[D_REL][GBK + APAD];

  const int t = threadIdx.x;
  const int w = t >> 6;
  const int lane = t & 63;
  const int quad = lane >> 4;
  const int l16 = lane & 15;
  const int block_row = blockIdx.x * GBM;

  f32x4 acc[4][4];
#pragma unroll
  for (int i = 0; i < 4; ++i)
#pragma unroll
    for (int j = 0; j < 4; ++j) acc[i][j] = (f32x4)(0.0f);

  for (int k0 = 0; k0 < D_SRC; k0 += GBK) {
    // Stage A tile: 128x32 fp32 -> bf16. 1024 float4 loads; 4 per thread.
#pragma unroll
    for (int i = 0; i < 4; ++i) {
      int linear = t + 256 * i;       // 0..1023
      int row = linear >> 3;          // 0..127
      int c4 = (linear & 7) << 2;     // 0..28
      int grow = block_row + row;
      float4 v = make_float4(0.f, 0.f, 0.f, 0.f);
      if (grow < M) v = *(const float4*)(A + (size_t)grow * D_SRC + k0 + c4);
      ushort4 pk;
      pk.x = f2bf(v.x); pk.y = f2bf(v.y); pk.z = f2bf(v.z); pk.w = f2bf(v.w);
      *(ushort4*)(&As[row][c4]) = pk;
    }
    // Stage B tile: WT[n][k0..k0+31], 128 rows x 64B. 512 x 16B loads; 2 per thread.
#pragma unroll
    for (int i = 0; i < 2; ++i) {
      int linear = t + 256 * i;       // 0..511
      int n = linear >> 2;            // 0..127
      int part = (linear & 3) << 3;   // 0,8,16,24 (shorts)
      *(uint4*)(&Bs[n][part]) = *(const uint4*)(WT + (size_t)n * D_SRC + k0 + part);
    }
    __syncthreads();

    bf16x8 af[4], bfr[4];
#pragma unroll
    for (int i = 0; i < 4; ++i)
      af[i] = *(const bf16x8*)(&As[(w >> 1) * 64 + i * 16 + l16][quad * 8]);
#pragma unroll
    for (int j = 0; j < 4; ++j)
      bfr[j] = *(const bf16x8*)(&Bs[(w & 1) * 64 + j * 16 + l16][quad * 8]);

#pragma unroll
    for (int i = 0; i < 4; ++i)
#pragma unroll
      for (int j = 0; j < 4; ++j)
        acc[i][j] = __builtin_amdgcn_mfma_f32_16x16x32_bf16(af[i], bfr[j], acc[i][j], 0, 0, 0);
    __syncthreads();
  }

  // Epilogue: C/D layout col=lane&15, row=quad*4+reg
  const int mb = block_row + (w >> 1) * 64;
  const int nb = (w & 1) * 64;
#pragma unroll
  for (int i = 0; i < 4; ++i) {
#pragma unroll
    for (int r = 0; r < 4; ++r) {
      int grow = mb + i * 16 + quad * 4 + r;
      if (grow < M) {
#pragma unroll
        for (int j = 0; j < 4; ++j) {
          int gcol = nb + j * 16 + l16;
          float val = acc[i][j][r];
          C[(size_t)grow * D_REL + gcol] = val;
          if (write_bf) Cbf[(size_t)grow * D_REL + gcol] = f2bf(val);
        }
      }
    }
  }
}

// ---------------- Degree count ----------------
__global__ __launch_bounds__(256) void deg_count(
    const int* __restrict__ edge_row, int E, int* __restrict__ cnt) {
  int i = blockIdx.x * blockDim.x + threadIdx.x;
  if (i < E) atomicAdd(&cnt[edge_row[i]], 1);
}

__global__ __launch_bounds__(256) void deg_finalize(
    const int* __restrict__ cnt, int n,
    float* __restrict__ deg_out, float* __restrict__ inv_deg) {
  int i = blockIdx.x * blockDim.x + threadIdx.x;
  if (i < n) {
    int c = cnt[i];
    float d = (float)(c > 1 ? c : 1);
    deg_out[i] = d;
    inv_deg[i] = 1.0f / d;
  }
}

// ---------------- Exclusive scan of cnt -> row_ptr ----------------
#define SCAN_B 256

__global__ __launch_bounds__(SCAN_B) void scan1(
    const int* __restrict__ cnt, int n,
    int* __restrict__ row_ptr, int* __restrict__ block_sums) {
  __shared__ int s[SCAN_B];
  int i = blockIdx.x * SCAN_B + threadIdx.x;
  int v = (i < n) ? cnt[i] : 0;
  s[threadIdx.x] = v;
  __syncthreads();
#pragma unroll
  for (int off = 1; off < SCAN_B; off <<= 1) {
    int add = (threadIdx.x >= off) ? s[threadIdx.x - off] : 0;
    __syncthreads();
    s[threadIdx.x] += add;
    __syncthreads();
  }
  if (i < n) row_ptr[i] = s[threadIdx.x] - v;
  if (threadIdx.x == SCAN_B - 1) block_sums[blockIdx.x] = s[SCAN_B - 1];
}

__global__ __launch_bounds__(512) void scan2(
    int* __restrict__ block_sums, int nblocks) {
  __shared__ int s[512];
  int v = (threadIdx.x < nblocks) ? block_sums[threadIdx.x] : 0;
  s[threadIdx.x] = v;
  __syncthreads();
#pragma unroll
  for (int off = 1; off < 512; off <<= 1) {
    int add = (threadIdx.x >= off) ? s[threadIdx.x - off] : 0;
    __syncthreads();
    s[threadIdx.x] += add;
    __syncthreads();
  }
  if (threadIdx.x < nblocks) block_sums[threadIdx.x] = s[threadIdx.x] - v;
}

__global__ __launch_bounds__(SCAN_B) void scan3(
    int* __restrict__ row_ptr, const int* __restrict__ block_sums,
    int* __restrict__ cursor, int n, int E) {
  int i = blockIdx.x * SCAN_B + threadIdx.x;
  if (i < n) {
    int v = row_ptr[i] + block_sums[blockIdx.x];
    row_ptr[i] = v;
    cursor[i] = v;
  }
  if (i == 0) row_ptr[n] = E;
}

// ---------------- Scatter edges into CSR order ----------------
__global__ __launch_bounds__(256) void scatter_edges(
    const int* __restrict__ edge_row, const int* __restrict__ edge_col,
    int* __restrict__ cursor, int* __restrict__ sorted_col, int E) {
  int e = blockIdx.x * blockDim.x + threadIdx.x;
  if (e < E) {
    int r = edge_row[e];
    int pos = atomicAdd(&cursor[r], 1);
    sorted_col[pos] = edge_col[e];
  }
}

// ---------------- CSR aggregate (bf16 gather): one wave per dst row ----------------
__global__ __launch_bounds__(256) void aggregate_csr_bf16(
    const int* __restrict__ row_ptr, const int* __restrict__ sorted_col,
    const unsigned short* __restrict__ srcb, const float* __restrict__ inv_deg,
    float* __restrict__ dst, int n) {
  int wave = (blockIdx.x * blockDim.x + threadIdx.x) >> 6;
  int lane = threadIdx.x & 63;
  if (wave >= n) return;
  int beg = row_ptr[wave];
  int end = row_ptr[wave + 1];
  const unsigned short* base = srcb + lane * 2;
  float ax = 0.f, ay = 0.f, bx = 0.f, by = 0.f;
  int e = beg;
  for (; e + 1 < end; e += 2) {
    unsigned u0 = *(const unsigned*)(base + (size_t)sorted_col[e] * D_REL);
    unsigned u1 = *(const unsigned*)(base + (size_t)sorted_col[e + 1] * D_REL);
    ax += __uint_as_float(u0 << 16);
    ay += __uint_as_float(u0 & 0xffff0000u);
    bx += __uint_as_float(u1 << 16);
    by += __uint_as_float(u1 & 0xffff0000u);
  }
  if (e < end) {
    unsigned u0 = *(const unsigned*)(base + (size_t)sorted_col[e] * D_REL);
    ax += __uint_as_float(u0 << 16);
    ay += __uint_as_float(u0 & 0xffff0000u);
  }
  float wgt = inv_deg[wave];
  float2 o;
  o.x = (ax + bx) * wgt;
  o.y = (ay + by) * wgt;
  *(float2*)(dst + (size_t)wave * D_REL + lane * 2) = o;
}

// ---------------- CSR aggregate (fp32 gather fallback) ----------------
__global__ __launch_bounds__(256) void aggregate_csr(
    const int* __restrict__ row_ptr, const int* __restrict__ sorted_col,
    const float* __restrict__ src_proj, const float* __restrict__ inv_deg,
    float* __restrict__ dst, int n) {
  int wave = (blockIdx.x * blockDim.x + threadIdx.x) >> 6;
  int lane = threadIdx.x & 63;
  if (wave >= n) return;
  int beg = row_ptr[wave];
  int end = row_ptr[wave + 1];
  const float* base = src_proj + lane * 2;
  float ax = 0.f, ay = 0.f, bx = 0.f, by = 0.f;
  int e = beg;
  for (; e + 1 < end; e += 2) {
    int c0 = sorted_col[e];
    int c1 = sorted_col[e + 1];
    float2 v0 = *(const float2*)(base + (size_t)c0 * D_REL);
    float2 v1 = *(const float2*)(base + (size_t)c1 * D_REL);
    ax += v0.x; ay += v0.y;
    bx += v1.x; by += v1.y;
  }
  if (e < end) {
    int c0 = sorted_col[e];
    float2 v0 = *(const float2*)(base + (size_t)c0 * D_REL);
    ax += v0.x; ay += v0.y;
  }
  float w = inv_deg[wave];
  float2 o;
  o.x = (ax + bx) * w;
  o.y = (ay + by) * w;
  *(float2*)(dst + (size_t)wave * D_REL + lane * 2) = o;
}

extern "C" void kernel_launch(void* const* d_in, const int* in_sizes, int n_in,
                              void* d_out, int out_size, void* d_ws, size_t ws_size,
                              hipStream_t stream) {
  const float* x_src = (const float*)d_in[0];
  // d_in[1] = x_dst, d_in[3] = W_dst: dead (dst_proj is deleted in reference)
  const float* W_src = (const float*)d_in[2];
  const int* edge_row = (const int*)d_in[4];
  const int* edge_col = (const int*)d_in[5];

  const int M = in_sizes[0] / D_SRC;   // N_SRC = 100000
  const int N = in_sizes[1] / 64;      // N_DST = 100000
  const int E = in_sizes[4];           // 640000

  float* out = (float*)d_out;
  float* out_dst = out;                                  // [N, 128]
  float* out_src_proj = out + (size_t)N * D_REL;         // [M, 128]
  float* out_deg = out_src_proj + (size_t)M * D_REL;     // [N]

  // Workspace layout (256B-aligned slabs)
  char* ws = (char*)d_ws;
  size_t off = 0;
  auto alloc = [&](size_t bytes) {
    char* p = ws + off;
    off = (off + bytes + 255) & ~(size_t)255;
    return p;
  };
  int* cnt        = (int*)alloc((size_t)N * sizeof(int));
  int* row_ptr    = (int*)alloc((size_t)(N + 1) * sizeof(int));
  int* cursor     = (int*)alloc((size_t)N * sizeof(int));
  int* sorted_col = (int*)alloc((size_t)E * sizeof(int));
  float* inv_deg  = (float*)alloc((size_t)N * sizeof(float));
  int* block_sums = (int*)alloc(512 * sizeof(int));
  unsigned short* WT = (unsigned short*)alloc((size_t)D_REL * D_SRC * sizeof(unsigned short));
  size_t base_need = off;
  unsigned short* src_bf = (unsigned short*)alloc((size_t)M * D_REL * sizeof(unsigned short));
  const bool use_bf = (ws_size >= off);
  (void)base_need;

  const int scan_blocks = (N + SCAN_B - 1) / SCAN_B;  // 391 <= 512

  hipMemsetAsync(cnt, 0, (size_t)N * sizeof(int), stream);

  // W^T bf16
  convert_wt<<<(D_SRC * D_REL) / 256, 256, 0, stream>>>(W_src, WT);

  // Degree + inv_deg
  deg_count<<<(E + 255) / 256, 256, 0, stream>>>(edge_row, E, cnt);
  deg_finalize<<<(N + 255) / 256, 256, 0, stream>>>(cnt, N, out_deg, inv_deg);

  // Exclusive scan cnt -> row_ptr; cursor = row_ptr
  scan1<<<scan_blocks, SCAN_B, 0, stream>>>(cnt, N, row_ptr, block_sums);
  scan2<<<1, 512, 0, stream>>>(block_sums, scan_blocks);
  scan3<<<scan_blocks, SCAN_B, 0, stream>>>(row_ptr, block_sums, cursor, N, E);

  // CSR scatter
  scatter_edges<<<(E + 255) / 256, 256, 0, stream>>>(edge_row, edge_col, cursor,
                                                     sorted_col, E);

  // MFMA GEMM: src_proj fp32 (+ bf16 copy for the gather if ws allows)
  gemm_mfma<<<(M + GBM - 1) / GBM, 256, 0, stream>>>(
      x_src, WT, out_src_proj, src_bf, M, use_bf ? 1 : 0);

  // Gather-aggregate: 1 wave per dst row, 4 waves per block
  if (use_bf) {
    aggregate_csr_bf16<<<(N + 3) / 4, 256, 0, stream>>>(row_ptr, sorted_col, src_bf,
                                                        inv_deg, out_dst, N);
  } else {
    aggregate_csr<<<(N + 3) / 4, 256, 0, stream>>>(row_ptr, sorted_col, out_src_proj,
                                                   inv_deg, out_dst, N);
  }
}